// Round 6
// baseline (419.900 us; speedup 1.0000x reference)
//
#include <hip/hip_runtime.h>
#include <hip/hip_bf16.h>

// SelfAttention2D: B=4, C=256, H=W=64, N=4096, Cqk=32.
// Round 15: barrier-free register-P flash attention.
//  R9-R14 evidence: per-step cost ~3100 cyc vs ~500 cyc issue work; the
//  barrier-locked chain (QK->exp->pack->ds_write->lgkm0->barrier->ds_read->PV)
//  is the bottleneck; occupancy plays (R10/R13/R14) all failed to beat it.
//  Key fact: the sigma-permuted Kp layout makes the packed ppv ALREADY a
//  valid PV B-operand for the wave's own 32-key window (R9's cj==srt bypass).
//  The LDS P-exchange existed only because PV was channel-split. This round:
//  waves = (rt 4) x (kh 2); each wave: S for its 16-row tile x its 32-key
//  window (2 QK MFMAs, unchanged), then PV for ALL 256 ch x its rows
//  (16 MFMAs, O[16], V as A-operand, ct=0..15). P never leaves registers.
//  NO LDS, NO barriers in the main loop -> waves are independent streams,
//  HW scoreboarding overlaps steps. S computed once per (row,key); O kh
//  partials combined in a 2-round LDS epilogue (35328 B static).
//  V reads duplicated 4x across rt-waves -> L1/L2 (per-XCD set ~3MB < 4MB L2).
// Keeps: permuted-K sigma layout, Q pre-scaled by log2e, truncating bf16
// pack via v_perm, K double-buffer prefetch, XCD-pair batch mapping.

typedef __attribute__((ext_vector_type(8))) short s8v;  // 8 bf16 (MFMA A/B frag)
typedef __attribute__((ext_vector_type(4))) float f4v;  // MFMA C/D frag

#define NPIX 4096
#define CIN 256
#define DQK 32

#if __has_builtin(__builtin_amdgcn_exp2f)
#define EXP2(x) __builtin_amdgcn_exp2f(x)
#else
#define EXP2(x) exp2f(x)
#endif

static __device__ __forceinline__ unsigned short f2bf(float f) {
    union { float f; unsigned int u; } v; v.f = f;
    unsigned int r = v.u + 0x7FFF + ((v.u >> 16) & 1);   // RTNE
    return (unsigned short)(r >> 16);
}
static __device__ __forceinline__ unsigned int fbits(float f) {
    union { float f; unsigned int u; } v; v.f = f; return v.u;
}

// ---------------------------------------------------------------------------
// Kernel 1: pack Wq/Wk/Wv -> bf16 Wall[320][256], biases -> fp32 ball[320].
__global__ void wcast_kernel(const float* __restrict__ Wq, const float* __restrict__ bq,
                             const float* __restrict__ Wk, const float* __restrict__ bk,
                             const float* __restrict__ Wv, const float* __restrict__ bv,
                             unsigned short* __restrict__ Wall, float* __restrict__ ball) {
    int row = blockIdx.x;
    int t = threadIdx.x;
    const float* src; const float* bsrc;
    if (row < 32)       { src = Wq + row * 256;        bsrc = bq + row; }
    else if (row < 64)  { src = Wk + (row - 32) * 256; bsrc = bk + (row - 32); }
    else                { src = Wv + (row - 64) * 256; bsrc = bv + (row - 64); }
    Wall[row * 256 + t] = f2bf(src[t]);
    if (t == 0) ball[row] = bsrc[0];
}

// ---------------------------------------------------------------------------
// Kernel 2: x[b][c][n] fp32 -> xT[b][n][c] bf16 (64x64 LDS tile transpose).
__global__ void tcast_kernel(const float* __restrict__ x, unsigned short* __restrict__ xT) {
    __shared__ unsigned short tile[64][65];
    int bidx = blockIdx.x;
    int b    = bidx >> 8;
    int cblk = (bidx >> 6) & 3;
    int nblk = bidx & 63;
    int t = threadIdx.x;
    int c0 = cblk * 64, n0 = nblk * 64;
    const float* xb = x + (size_t)b * CIN * NPIX;
    #pragma unroll
    for (int p = 0; p < 4; p++) {
        int cl = p * 16 + (t >> 4);
        int nl = (t & 15) * 4;
        float4 v = *(const float4*)(xb + (size_t)(c0 + cl) * NPIX + n0 + nl);
        tile[cl][nl + 0] = f2bf(v.x);
        tile[cl][nl + 1] = f2bf(v.y);
        tile[cl][nl + 2] = f2bf(v.z);
        tile[cl][nl + 3] = f2bf(v.w);
    }
    __syncthreads();
    unsigned short* xTb = xT + (size_t)b * NPIX * CIN;
    #pragma unroll
    for (int p = 0; p < 4; p++) {
        int nl = p * 16 + (t >> 4);
        int cl = (t & 15) * 4;
        ushort4 wv;
        wv.x = tile[cl + 0][nl];
        wv.y = tile[cl + 1][nl];
        wv.z = tile[cl + 2][nl];
        wv.w = tile[cl + 3][nl];
        *(ushort4*)(xTb + (size_t)(n0 + nl) * CIN + c0 + cl) = wv;
    }
}

// ---------------------------------------------------------------------------
// Kernel 3: projection GEMM (R4-verified). grid = 256, 4 waves x 16 n-rows.
__global__ __launch_bounds__(256)
void proj_kernel(const unsigned short* __restrict__ xT,
                 const unsigned short* __restrict__ Wall,
                 const float* __restrict__ ball,
                 unsigned short* __restrict__ Q,
                 unsigned short* __restrict__ Kp,
                 unsigned short* __restrict__ Vt) {
    int idx  = blockIdx.x;
    int b    = (idx & 7) >> 1;
    int nblk = ((idx >> 3) << 1) | (idx & 1);
    int w    = threadIdx.x >> 6;
    int lane = threadIdx.x & 63;
    int l16 = lane & 15, quad = lane >> 4;
    int n0 = nblk * 64 + w * 16;

    const unsigned short* brow = xT + (size_t)(b * NPIX + n0 + l16) * CIN + quad * 8;
    s8v bfr[8];
    #pragma unroll
    for (int kk = 0; kk < 8; kk++) bfr[kk] = *(const s8v*)(brow + kk * 32);

    #pragma unroll
    for (int p = 0; p < 10; p++) {
        const unsigned short* w0 = Wall + (size_t)(2 * p * 16 + l16) * CIN + quad * 8;
        const unsigned short* w1 = w0 + 16 * CIN;
        f4v a0 = {0.f, 0.f, 0.f, 0.f}, a1 = {0.f, 0.f, 0.f, 0.f};
        if (p < 2) {  // Q/K: A=xT(rows=n), B=W(cols=oc)
            #pragma unroll
            for (int kk = 0; kk < 8; kk++) {
                a0 = __builtin_amdgcn_mfma_f32_16x16x32_bf16(bfr[kk], *(const s8v*)(w0 + kk * 32), a0, 0, 0, 0);
                a1 = __builtin_amdgcn_mfma_f32_16x16x32_bf16(bfr[kk], *(const s8v*)(w1 + kk * 32), a1, 0, 0, 0);
            }
        } else {      // V: A=W(rows=ch), B=xT(cols=n)
            #pragma unroll
            for (int kk = 0; kk < 8; kk++) {
                a0 = __builtin_amdgcn_mfma_f32_16x16x32_bf16(*(const s8v*)(w0 + kk * 32), bfr[kk], a0, 0, 0, 0);
                a1 = __builtin_amdgcn_mfma_f32_16x16x32_bf16(*(const s8v*)(w1 + kk * 32), bfr[kk], a1, 0, 0, 0);
            }
        }
        #pragma unroll
        for (int half = 0; half < 2; half++) {
            int ob = 2 * p + half;
            f4v acc = half ? a1 : a0;
            if (ob < 2) {            // Q: lane l16 = oc, reg r -> n-sub
                int oc = ob * 16 + l16;
                float bias = ball[oc];
                #pragma unroll
                for (int r = 0; r < 4; r++) {
                    int n = n0 + quad * 4 + r;
                    Q[(size_t)(b * NPIX + n) * DQK + oc] =
                        f2bf((acc[r] + bias) * 1.44269504f);
                }
            } else if (ob < 4) {     // K~: permuted row sigma^-1(n)
                int oc = (ob - 2) * 16 + l16;
                float bias = ball[32 + oc];
                #pragma unroll
                for (int r = 0; r < 4; r++) {
                    int n = n0 + quad * 4 + r;
                    int pn = (n & ~31) | (((n >> 2) & 1) << 4) | (((n >> 3) & 3) << 2) | (n & 3);
                    Kp[(size_t)(b * NPIX + pn) * DQK + oc] = f2bf(acc[r] + bias);
                }
            } else {                 // V: lane l16 = n, reg r -> ch-sub
                int n = n0 + l16;
                #pragma unroll
                for (int r = 0; r < 4; r++) {
                    int ch = (ob - 4) * 16 + quad * 4 + r;
                    Vt[((size_t)b * CIN + ch) * NPIX + n] = f2bf(acc[r] + ball[64 + ch]);
                }
            }
        }
    }
}

// ---------------------------------------------------------------------------
// Kernel 4: barrier-free register-P flash attention.
// grid 256 (1 block/CU), 512 threads = 8 waves: (kh = w>>2) x (rt = w&3).
// Wave: S for rows rt*16..+16, keys [kh*32 + t*64, +32) per step t=0..63;
// ppv (packed P) consumed in-register as PV B-operand; PV over all 256 ch.
#define ATTN_STEP(S, KC0, KC1, KN0, KN1)                                        \
    {                                                                           \
        const int kvn = ((S) + 1) & 63;                                         \
        KN0 = *(const s8v*)(kbase + (size_t)(kvn * 64) * DQK);                  \
        KN1 = *(const s8v*)(kbase + (size_t)(kvn * 64 + 16) * DQK);             \
        f4v s0 = {0.f, 0.f, 0.f, 0.f}, s1 = {0.f, 0.f, 0.f, 0.f};               \
        s0 = __builtin_amdgcn_mfma_f32_16x16x32_bf16(KC0, qf, s0, 0, 0, 0);     \
        s1 = __builtin_amdgcn_mfma_f32_16x16x32_bf16(KC1, qf, s1, 0, 0, 0);     \
        float p00 = EXP2(s0[0]), p01 = EXP2(s0[1]);                             \
        float p02 = EXP2(s0[2]), p03 = EXP2(s0[3]);                             \
        float p10 = EXP2(s1[0]), p11 = EXP2(s1[1]);                             \
        float p12 = EXP2(s1[2]), p13 = EXP2(s1[3]);                             \
        lsum += ((p00 + p01) + (p02 + p03)) + ((p10 + p11) + (p12 + p13));      \
        union { uint4 u; s8v v; } pp;                                           \
        pp.u.x = __builtin_amdgcn_perm(fbits(p01), fbits(p00), 0x07060302);     \
        pp.u.y = __builtin_amdgcn_perm(fbits(p03), fbits(p02), 0x07060302);     \
        pp.u.z = __builtin_amdgcn_perm(fbits(p11), fbits(p10), 0x07060302);     \
        pp.u.w = __builtin_amdgcn_perm(fbits(p13), fbits(p12), 0x07060302);     \
        const unsigned short* vwin = vbase + (S) * 64;                          \
        _Pragma("unroll")                                                       \
        for (int ct = 0; ct < 16; ct++) {                                       \
            s8v vf = *(const s8v*)(vwin + (size_t)ct * 16 * NPIX);              \
            O[ct] = __builtin_amdgcn_mfma_f32_16x16x32_bf16(vf, pp.v, O[ct], 0, 0, 0); \
        }                                                                       \
    }

__global__ __launch_bounds__(512)
void attn_kernel(const unsigned short* __restrict__ Q,
                 const unsigned short* __restrict__ Kp,
                 const unsigned short* __restrict__ Vt,
                 const float* __restrict__ gamma,
                 float* __restrict__ out) {
    // LDS only for epilogue: ldsO [2][64][68] f32 = 34816 B + ldsL 512 B.
    __shared__ __align__(16) char smem[35328];

    int idx = blockIdx.x;
    int b      = (idx & 7) >> 1;                    // batch -> XCD pair
    int rowblk = ((idx >> 3) << 1) | (idx & 1);     // 0..63

    int lane = threadIdx.x & 63;
    int w    = threadIdx.x >> 6;
    int l16 = lane & 15, quad = lane >> 4;
    int kh = w >> 2;     // key 32-half within 64-key step
    int rt = w & 3;      // row-tile (16 rows)

    const unsigned short* Kb = Kp + (size_t)b * NPIX * DQK;
    const unsigned short* Vb = Vt + (size_t)b * CIN * NPIX;

    int rowbase = rowblk * 64;
    const s8v qf = *(const s8v*)(Q + (size_t)(b * NPIX + rowbase + rt * 16 + l16) * DQK + quad * 8);

    const unsigned short* kbase = Kb + (32 * kh + l16) * DQK + quad * 8;
    const unsigned short* vbase = Vb + (size_t)l16 * NPIX + 32 * kh + quad * 8;

    f4v O[16];
    #pragma unroll
    for (int ct = 0; ct < 16; ct++) O[ct] = (f4v){0.f, 0.f, 0.f, 0.f};
    float lsum = 0.f;

    s8v Kc0, Kc1, Kn0, Kn1;
    Kc0 = *(const s8v*)(kbase);
    Kc1 = *(const s8v*)(kbase + 16 * DQK);

    // ---- 64 independent steps, no barriers, K double-buffered ----
    for (int p = 0; p < 32; p++) {
        ATTN_STEP(2 * p,     Kc0, Kc1, Kn0, Kn1);
        ATTN_STEP(2 * p + 1, Kn0, Kn1, Kc0, Kc1);
    }

    // row-sum partial (rows rt-tile, this wave's 2048 keys): reduce quads
    lsum += __shfl_xor(lsum, 16);
    lsum += __shfl_xor(lsum, 32);

    float (*ldsO)[64][68] = (float (*)[64][68])smem;          // [rt&1][lane][16 f4v + pad]
    float* ldsL = (float*)(smem + 34816);                     // [kh][rt][16]

    if (quad == 0) ldsL[(kh * 4 + rt) * 16 + l16] = lsum;

    // ---- round A: rt 0,1 kh-combine; round B: rt 2,3 ----
    #pragma unroll
    for (int rnd = 0; rnd < 2; rnd++) {
        if (kh == 1 && (rt >> 1) == rnd) {
            #pragma unroll
            for (int ct = 0; ct < 16; ct++)
                *(f4v*)&ldsO[rt & 1][lane][ct * 4] = O[ct];
        }
        __syncthreads();
        if (kh == 0 && (rt >> 1) == rnd) {
            float g = gamma[0];
            float rinv = g / (ldsL[rt * 16 + l16] + ldsL[(4 + rt) * 16 + l16]);
            #pragma unroll
            for (int ct = 0; ct < 16; ct++) {
                f4v o2 = *(const f4v*)&ldsO[rt & 1][lane][ct * 4];
                #pragma unroll
                for (int r = 0; r < 4; r++) {
                    int ch = ct * 16 + quad * 4 + r;
                    out[((size_t)b * CIN + ch) * NPIX + rowbase + rt * 16 + l16] =
                        (O[ct][r] + o2[r]) * rinv;
                }
            }
        }
        __syncthreads();
    }
}

// ---------------------------------------------------------------------------
extern "C" void kernel_launch(void* const* d_in, const int* in_sizes, int n_in,
                              void* d_out, int out_size, void* d_ws, size_t ws_size,
                              hipStream_t stream) {
    const float* x     = (const float*)d_in[0];
    const float* Wq    = (const float*)d_in[1];
    const float* bq    = (const float*)d_in[2];
    const float* Wk    = (const float*)d_in[3];
    const float* bk    = (const float*)d_in[4];
    const float* Wv    = (const float*)d_in[5];
    const float* bv    = (const float*)d_in[6];
    const float* gamma = (const float*)d_in[7];
    float* out = (float*)d_out;

    char* p = (char*)d_ws;
    unsigned short* xT   = (unsigned short*)p; p += (size_t)4 * NPIX * CIN * 2;   // 8 MB
    unsigned short* Qb   = (unsigned short*)p; p += (size_t)4 * NPIX * DQK * 2;   // 1 MB
    unsigned short* Kb   = (unsigned short*)p; p += (size_t)4 * NPIX * DQK * 2;   // 1 MB
    unsigned short* Vt   = (unsigned short*)p; p += (size_t)4 * CIN * NPIX * 2;   // 8 MB
    unsigned short* Wall = (unsigned short*)p; p += (size_t)320 * 256 * 2;
    float*          ball = (float*)p;          p += (size_t)320 * 4;

    wcast_kernel<<<320, 256, 0, stream>>>(Wq, bq, Wk, bk, Wv, bv, Wall, ball);
    tcast_kernel<<<1024, 256, 0, stream>>>(x, xT);
    proj_kernel<<<256, 256, 0, stream>>>(xT, Wall, ball, Qb, Kb, Vt);
    attn_kernel<<<256, 512, 0, stream>>>(Qb, Kb, Vt, gamma, out);
}